// Round 11
// baseline (71.375 us; speedup 1.0000x reference)
//
#include <hip/hip_runtime.h>

// ============================================================================
// R11 ATTRIBUTION PROBE: kernels are bit-identical to R10 (best, 64.2us).
// enc_mfma is launched TWICE (idempotent: deterministic partials, identical
// bytes both times -> output unchanged). dur_R11 - dur_R10 = enc + 1 gap.
// This resolves the 3-round-old ~13us unattributed kernel-side residual:
//   ~67-69us => enc small; residual is reduce/overhead floor -> R12 fusion.
//   ~78-82us => enc is the pocket -> R12 attacks enc staging/occupancy.
// ============================================================================

#define G_TOTAL 16384            // 128 x 128 grid
#define NPTS    8192
#define CI      128              // context points per block chunk
#define NSPLIT  64               // 8192 / CI  -> grid 256 = 1 block/CU
#define LDA     136              // LDS row pitch in halves (128 + 8 pad)
#define PBLK    12288            // partial halves per block: 4w x 12f x 64l x 4r

typedef _Float16 f16;
typedef f16  f16x8 __attribute__((ext_vector_type(8)));
typedef f16  f16x4 __attribute__((ext_vector_type(4)));
typedef float f32x4 __attribute__((ext_vector_type(4)));

// Raw v_exp_f32 — args in [-40, 0]: no denormal/range fixup needed.
__device__ __forceinline__ float fast_exp2(float x) {
#if __has_builtin(__builtin_amdgcn_exp2f)
    return __builtin_amdgcn_exp2f(x);
#else
    float r; asm("v_exp_f32 %0, %1" : "=v"(r) : "v"(x)); return r;
#endif
}

// ---------------------------------------------------------------------------
// MFMA factorized kernel (identical to R10).
// ---------------------------------------------------------------------------
__global__ __launch_bounds__(256) void enc_mfma(
    const float* __restrict__ X,   // (8192, 2) positions
    const float* __restrict__ Y,   // (8192, 2) labels
    f16* __restrict__ wsP)         // partials [tile][s][PBLK]
{
    __shared__ f16 ExT[128 * LDA];     // [j][i]    34.8 KB
    __shared__ f16 Ey3[3 * 32 * LDA];  // [c][k][i] 26.1 KB

    const int t    = threadIdx.x;
    const int b    = blockIdx.x;
    const int tile = b & 3;            // k band: kb = tile*32
    const int sidx = b >> 2;           // split 0..63
    const int c0   = sidx * CI;
    const int kb   = tile * 32;

    const float sc   = 0.84932184f;    // sqrt(0.5 * log2(e))
    const float step = 4.0f / 127.0f;

    const float2* X2 = (const float2*)X;
    const float2* Y2 = (const float2*)Y;

    // ---- stage ExT[j][i], fp16: thread -> (j = t>>1, 64-i half)
    {
        const int   j  = t >> 1, ih = (t & 1) * 64;
        const float gx = (-2.0f + step * (float)j) * sc;
#pragma unroll
        for (int u = 0; u < 8; ++u) {
            f16x8 v;
#pragma unroll
            for (int e = 0; e < 8; ++e) {
                const int   i = ih + u * 8 + e;
                const float d = gx - X2[c0 + i].x * sc;
                v[e] = (f16)fast_exp2(-d * d);
            }
            *(f16x8*)&ExT[j * LDA + ih + u * 8] = v;
        }
    }
    // ---- stage Ey3[c][k][i], channels baked: thread -> (k = t>>3, 16-i blk)
    {
        const int   k  = t >> 3, ib = (t & 7) * 16;
        const float gy = (2.0f - step * (float)(kb + k)) * sc;
#pragma unroll
        for (int u = 0; u < 2; ++u) {
            f16x8 v0, v1, v2;
#pragma unroll
            for (int e = 0; e < 8; ++e) {
                const int    i  = ib + u * 8 + e;
                const float  d  = gy - X2[c0 + i].y * sc;
                const float  ee = fast_exp2(-d * d);
                const float2 yv = Y2[c0 + i];
                v0[e] = (f16)ee;
                v1[e] = (f16)(ee * yv.x);
                v2[e] = (f16)(ee * yv.y);
            }
            *(f16x8*)&Ey3[(0 * 32 + k) * LDA + ib + u * 8] = v0;
            *(f16x8*)&Ey3[(1 * 32 + k) * LDA + ib + u * 8] = v1;
            *(f16x8*)&Ey3[(2 * 32 + k) * LDA + ib + u * 8] = v2;
        }
    }
    __syncthreads();

    // ---- MFMA: wave w owns j in [32w, 32w+32). 48 mfma per wave (4 ksteps).
    const int w    = t >> 6;
    const int lane = t & 63;
    const int l15  = lane & 15;
    const int lk8  = (lane >> 4) * 8;

    f32x4 acc[12];                     // [c*4 + kt*2 + jt]
#pragma unroll
    for (int z = 0; z < 12; ++z) acc[z] = (f32x4){0.f, 0.f, 0.f, 0.f};

#pragma unroll
    for (int ks = 0; ks < 4; ++ks) {
        const int io = ks * 32 + lk8;
        const f16x8 bf0 = *(const f16x8*)&ExT[(w * 32 +      l15) * LDA + io];
        const f16x8 bf1 = *(const f16x8*)&ExT[(w * 32 + 16 + l15) * LDA + io];
#pragma unroll
        for (int c = 0; c < 3; ++c) {
            const f16x8 a0 = *(const f16x8*)&Ey3[(c * 32 +      l15) * LDA + io];
            const f16x8 a1 = *(const f16x8*)&Ey3[(c * 32 + 16 + l15) * LDA + io];
            acc[c*4+0] = __builtin_amdgcn_mfma_f32_16x16x32_f16(a0, bf0, acc[c*4+0], 0, 0, 0);
            acc[c*4+1] = __builtin_amdgcn_mfma_f32_16x16x32_f16(a0, bf1, acc[c*4+1], 0, 0, 0);
            acc[c*4+2] = __builtin_amdgcn_mfma_f32_16x16x32_f16(a1, bf0, acc[c*4+2], 0, 0, 0);
            acc[c*4+3] = __builtin_amdgcn_mfma_f32_16x16x32_f16(a1, bf1, acc[c*4+3], 0, 0, 0);
        }
    }

    // ---- fragment-native fp16 partial store: lane-contiguous h4, coalesced.
    f16* P = wsP + (size_t)(tile * NSPLIT + sidx) * PBLK;
#pragma unroll
    for (int f = 0; f < 12; ++f) {
        f16x4 pv;
        pv[0] = (f16)acc[f][0];  pv[1] = (f16)acc[f][1];
        pv[2] = (f16)acc[f][2];  pv[3] = (f16)acc[f][3];
        *(f16x4*)&P[((w * 12 + f) * 64 + lane) * 4] = pv;
    }
}

// ---------------------------------------------------------------------------
// Reduce + normalize (identical to R10).
// ---------------------------------------------------------------------------
__global__ __launch_bounds__(512) void reduce_norm(
    const f16* __restrict__ wsP, float* __restrict__ out)
{
    __shared__ f32x4 sm[8][3][64];     // [sq][c][lane] : 24 KB

    const int bx   = blockIdx.x;
    const int tile = bx >> 4;
    const int w    = (bx >> 2) & 3;
    const int q    = bx & 3;           // kt*2 + jt
    const int t    = threadIdx.x;
    const int lane = t & 63;
    const int sq   = t >> 6;           // 0..7

    const f16x4* base = (const f16x4*)wsP;   // h4 units; PBLK/4 = 3072 per s
    const int slot = (w * 12 + q) * 64 + lane;

    f32x4 s0 = {0.f,0.f,0.f,0.f}, s1 = s0, s2 = s0;
#pragma unroll 8
    for (int s = sq * 8; s < sq * 8 + 8; ++s) {
        const size_t bo = (size_t)(tile * NSPLIT + s) * 3072 + slot;
        const f16x4 h0 = base[bo];           // c=0 (offset c*256)
        const f16x4 h1 = base[bo + 256];     // c=1
        const f16x4 h2 = base[bo + 512];     // c=2
#pragma unroll
        for (int r = 0; r < 4; ++r) {
            s0[r] += (float)h0[r];
            s1[r] += (float)h1[r];
            s2[r] += (float)h2[r];
        }
    }
    sm[sq][0][lane] = s0;
    sm[sq][1][lane] = s1;
    sm[sq][2][lane] = s2;
    __syncthreads();

    if (t < 64) {
        f32x4 f0 = {0.f,0.f,0.f,0.f}, f1 = f0, f2 = f0;
#pragma unroll
        for (int u = 0; u < 8; ++u) {
#pragma unroll
            for (int r = 0; r < 4; ++r) {
                f0[r] += sm[u][0][t][r];
                f1[r] += sm[u][1][t][r];
                f2[r] += sm[u][2][t][r];
            }
        }
        const int k0 = tile * 32 + (q >> 1) * 16 + (t >> 4) * 4;
        const int j  = w * 32 + (q & 1) * 16 + (t & 15);
#pragma unroll
        for (int r = 0; r < 4; ++r) {
            const int   g   = (k0 + r) * 128 + j;
            const float inv = 1.0f / f0[r];
            out[g]               = f0[r];
            out[G_TOTAL + g]     = f1[r] * inv;
            out[2 * G_TOTAL + g] = f2[r] * inv;
        }
    }
}

// ---------------------------------------------------------------------------
extern "C" void kernel_launch(void* const* d_in, const int* in_sizes, int n_in,
                              void* d_out, int out_size, void* d_ws, size_t ws_size,
                              hipStream_t stream) {
    const float* X = (const float*)d_in[0];
    const float* Y = (const float*)d_in[1];
    float* out = (float*)d_out;
    f16*  wsP = (f16*)d_ws;

    // PROBE: enc launched twice (idempotent). dur - dur_R10 = enc + 1 gap.
    enc_mfma<<<256, 256, 0, stream>>>(X, Y, wsP);   // 1 block/CU
    enc_mfma<<<256, 256, 0, stream>>>(X, Y, wsP);   // duplicate, same bytes
    reduce_norm<<<64, 512, 0, stream>>>(wsP, out);
}